// Round 1
// baseline (454.266 us; speedup 1.0000x reference)
//
#include <hip/hip_runtime.h>
#include <cstdint>
#include <cstddef>

#define B_ 2
#define S_ 2048
#define D_ 2048
#define H_ 32
#define KV_ 8
#define HD_ 64
#define M_ (B_*S_)      // 4096 rows total
#define EQ_ (H_*HD_)    // 2048
#define EK_ (KV_*HD_)   // 512

typedef unsigned short u16;
typedef __attribute__((ext_vector_type(8))) short s16x8;   // 8 x bf16 (4 VGPRs)
typedef __attribute__((ext_vector_type(4))) float f32x4;

// q pre-scale folds 1/sqrt(HD)=0.125 and log2(e) so flash uses raw 2^x
#define QSCALE 0.18033688011112042f      // 0.125 * log2(e)
#define EXPOFF 15.869645449778564f       // 11 * log2(e)

#if __has_builtin(__builtin_amdgcn_exp2f)
#define EXP2(x) __builtin_amdgcn_exp2f(x)
#else
#define EXP2(x) __expf((x) * 0.6931471805599453f)
#endif

__device__ __forceinline__ u16 f2bf(float f) {
  unsigned u = __float_as_uint(f);
  u += 0x7fffu + ((u >> 16) & 1u);        // RNE
  return (u16)(u >> 16);
}
// pack two floats to two bf16 in one dword via v_perm (proven path)
__device__ __forceinline__ unsigned pk2(float a, float b) {
  unsigned ua = __float_as_uint(a) + 0x8000u;
  unsigned ub = __float_as_uint(b) + 0x8000u;
  return __builtin_amdgcn_perm(ub, ua, 0x07060302);  // [ua.b2,ua.b3,ub.b2,ub.b3]
}
__device__ __forceinline__ f32x4 mfma16(s16x8 a, s16x8 b, f32x4 c) {
  return __builtin_amdgcn_mfma_f32_16x16x32_bf16(a, b, c, 0, 0, 0);
}
__device__ __forceinline__ void gl_lds16(const void* g, void* l) {
  __builtin_amdgcn_global_load_lds(
      (const __attribute__((address_space(1))) void*)g,
      (__attribute__((address_space(3))) void*)l, 16, 0, 0);
}

// ---------------- fused fp32 -> bf16 cast of all 5 inputs ----------------
__global__ void cast_all(const float4* __restrict__ x, const float4* __restrict__ wq,
                         const float4* __restrict__ wk, const float4* __restrict__ wv,
                         const float4* __restrict__ wo, ushort4* __restrict__ dst) {
  int i = blockIdx.x * 256 + threadIdx.x;
  const float4* src; int off;
  if (i < 2097152)      { src = x;  off = i; }
  else if (i < 3145728) { src = wq; off = i - 2097152; }
  else if (i < 3407872) { src = wk; off = i - 3145728; }
  else if (i < 3670016) { src = wv; off = i - 3407872; }
  else                  { src = wo; off = i - 3670016; }
  float4 v = src[off];
  ushort4 r;
  r.x = f2bf(v.x); r.y = f2bf(v.y); r.z = f2bf(v.z); r.w = f2bf(v.w);
  dst[i] = r;
}

// ---------------- fused QKV projection GEMM: 128x96 tile, BK=64, 4 blocks/CU ----------------
// C[m][n] = sum_k X[m][k] * W[n][k], W = [wq; wk; wv] (N=3072 contiguous).
// Grid (32,32)=1024 blocks = 4/CU. XOR-swizzled LDS (0 bank conflicts, R6-proven).
// Region boundaries (2048, 2560) are 16-multiples -> per-ni branch is wave-uniform.
__global__ __launch_bounds__(256)
void gemm_qkv(const u16* __restrict__ A, const u16* __restrict__ Bw,
              u16* __restrict__ qb, u16* __restrict__ kb, u16* __restrict__ vtb,
              const float* __restrict__ fc) {
  __shared__ __align__(16) u16 As[128 * 64];   // 16 KB
  __shared__ __align__(16) u16 Bs[96 * 64];    // 12 KB
  const int tid  = threadIdx.x;
  const int lane = tid & 63;
  const int wave = tid >> 6;
  const int m0 = blockIdx.y * 128;
  const int n0 = blockIdx.x * 96;
  const int wm = (wave >> 1) * 64;
  const int wn = (wave & 1) * 48;
  const int l15 = lane & 15;
  const int quad = lane >> 4;

  f32x4 acc[4][3] = {};

  for (int k0 = 0; k0 < D_; k0 += 64) {
    #pragma unroll
    for (int rr = 0; rr < 4; ++rr) {
      int c = tid + rr * 256;                 // 0..1023: row=c>>3 (0..127)
      int row = c >> 3;
      int ksrc = ((c & 7) ^ (row & 7)) * 8;
      gl_lds16(A + (size_t)(m0 + row) * D_ + k0 + ksrc, &As[c * 8]);
    }
    #pragma unroll
    for (int rr = 0; rr < 3; ++rr) {
      int c = tid + rr * 256;                 // 0..767: row=c>>3 (0..95)
      int row = c >> 3;
      int ksrc = ((c & 7) ^ (row & 7)) * 8;
      gl_lds16(Bw + (size_t)(n0 + row) * D_ + k0 + ksrc, &Bs[c * 8]);
    }
    __syncthreads();

    #pragma unroll
    for (int kc = 0; kc < 2; ++kc) {
      s16x8 af[4], bfr[3];
      #pragma unroll
      for (int mi = 0; mi < 4; ++mi) {
        int row = wm + mi * 16 + l15;
        af[mi]  = *(const s16x8*)&As[row * 64 + (((kc * 4 + quad) ^ (row & 7)) * 8)];
      }
      #pragma unroll
      for (int ni = 0; ni < 3; ++ni) {
        int row = wn + ni * 16 + l15;
        bfr[ni] = *(const s16x8*)&Bs[row * 64 + (((kc * 4 + quad) ^ (row & 7)) * 8)];
      }
      #pragma unroll
      for (int mi = 0; mi < 4; ++mi)
        #pragma unroll
        for (int ni = 0; ni < 3; ++ni)
          acc[mi][ni] = mfma16(af[mi], bfr[ni], acc[mi][ni]);
    }
    __syncthreads();
  }

  // ---- epilogue: per-ni region branch (wave-uniform) ----
  const float sg = (l15 & 1) ? 1.f : -1.f;
  #pragma unroll
  for (int mi = 0; mi < 4; ++mi) {
    #pragma unroll
    for (int ni = 0; ni < 3; ++ni) {
      const int col = n0 + wn + ni * 16 + l15;
      if (col < 2560) {
        // Q or K: fused RoPE (even lane: tr*c - ti*sn; odd: tr*sn + ti*c)
        const bool isQ = (col < 2048);
        u16* dst = isQ ? qb : kb;
        const int ncol0 = isQ ? 0 : 2048;
        const int ndim  = isQ ? EQ_ : EK_;
        const float scale = isQ ? QSCALE : 1.0f;
        const int ip = (col & 63) >> 1;
        #pragma unroll
        for (int r = 0; r < 4; ++r) {
          int row = m0 + wm + mi * 16 + quad * 4 + r;
          const float* fr = fc + (size_t)(row & (S_ - 1)) * 64;
          float c  = fr[ip * 2];
          float sn = fr[ip * 2 + 1];
          float v = acc[mi][ni][r];
          float p = __shfl_xor(v, 1, 64);
          float o = (v * c + sg * (p * sn)) * scale;
          dst[(size_t)row * ndim + col - ncol0] = f2bf(o);
        }
      } else {
        // V: transposed store, 4 consecutive rows per lane -> one 8B store
        const int vcol = col - 2560;
        uint2 w;
        w.x = pk2(acc[mi][ni][0], acc[mi][ni][1]);
        w.y = pk2(acc[mi][ni][2], acc[mi][ni][3]);
        *(uint2*)(vtb + (size_t)vcol * M_ + m0 + wm + mi * 16 + quad * 4) = w;
      }
    }
  }
}

// ---------------- O-projection GEMM: 64x128 tile, BK=64, 4 blocks/CU ----------------
// Grid (16,64)=1024 blocks. 4 waves as 2x2: wave = 32 rows x 64 cols (acc[2][4]).
__global__ __launch_bounds__(256)
void gemm_o(const u16* __restrict__ A, const u16* __restrict__ Bw, float* __restrict__ C,
            int Ndim, int Kdim) {
  __shared__ __align__(16) u16 As[64 * 64];    // 8 KB
  __shared__ __align__(16) u16 Bs[128 * 64];   // 16 KB
  const int tid  = threadIdx.x;
  const int lane = tid & 63;
  const int wave = tid >> 6;
  const int m0 = blockIdx.y * 64;
  const int n0 = blockIdx.x * 128;
  const int wm = (wave >> 1) * 32;
  const int wn = (wave & 1) * 64;
  const int l15 = lane & 15;
  const int quad = lane >> 4;

  f32x4 acc[2][4] = {};

  for (int k0 = 0; k0 < Kdim; k0 += 64) {
    #pragma unroll
    for (int rr = 0; rr < 2; ++rr) {
      int c = tid + rr * 256;                 // 0..511: row=c>>3 (0..63)
      int row = c >> 3;
      int ksrc = ((c & 7) ^ (row & 7)) * 8;
      gl_lds16(A + (size_t)(m0 + row) * Kdim + k0 + ksrc, &As[c * 8]);
    }
    #pragma unroll
    for (int rr = 0; rr < 4; ++rr) {
      int c = tid + rr * 256;                 // 0..1023: row=c>>3 (0..127)
      int row = c >> 3;
      int ksrc = ((c & 7) ^ (row & 7)) * 8;
      gl_lds16(Bw + (size_t)(n0 + row) * Kdim + k0 + ksrc, &Bs[c * 8]);
    }
    __syncthreads();

    #pragma unroll
    for (int kc = 0; kc < 2; ++kc) {
      s16x8 af[2], bfr[4];
      #pragma unroll
      for (int mi = 0; mi < 2; ++mi) {
        int row = wm + mi * 16 + l15;
        af[mi]  = *(const s16x8*)&As[row * 64 + (((kc * 4 + quad) ^ (row & 7)) * 8)];
      }
      #pragma unroll
      for (int ni = 0; ni < 4; ++ni) {
        int row = wn + ni * 16 + l15;
        bfr[ni] = *(const s16x8*)&Bs[row * 64 + (((kc * 4 + quad) ^ (row & 7)) * 8)];
      }
      #pragma unroll
      for (int mi = 0; mi < 2; ++mi)
        #pragma unroll
        for (int ni = 0; ni < 4; ++ni)
          acc[mi][ni] = mfma16(af[mi], bfr[ni], acc[mi][ni]);
    }
    __syncthreads();
  }

  #pragma unroll
  for (int mi = 0; mi < 2; ++mi) {
    #pragma unroll
    for (int r = 0; r < 4; ++r) {
      int row = m0 + wm + mi * 16 + quad * 4 + r;
      size_t base = (size_t)row * Ndim + n0 + wn;
      #pragma unroll
      for (int ni = 0; ni < 4; ++ni)
        C[base + ni * 16 + l15] = acc[mi][ni][r];
    }
  }
}

// ---------------- causal GQA flash attention v5 ----------------
// v4 + T14 async-STAGE split: per k-tile, each thread issues its 4x16B
// global loads for tile kt+1 into registers BEFORE computing tile kt,
// then ds_write_b128's them to Ks/Vs after the post-compute barrier.
// HBM/L2 latency (previously fully exposed at the vmcnt(0) barrier drain
// each tile) now hides under the ~600-800 cycle compute phase.
// Barrier count per tile unchanged (2). LDS unchanged (34 KB, 4 blocks/CU).
__global__ __launch_bounds__(256, 4)
void flash_attn(const u16* __restrict__ qb, const u16* __restrict__ kb,
                const u16* __restrict__ vtb, u16* __restrict__ ob) {
  const int bx = blockIdx.x;        // 0..15
  const int h  = blockIdx.y;
  const int b  = blockIdx.z;
  const int g  = h >> 2;            // REP=4
  const int tid  = threadIdx.x;
  const int lane = tid & 63;
  const int wave = tid >> 6;
  const int l15  = lane & 15;
  const int quad = lane >> 4;
  const int kq   = quad * 8;

  const int Tlo = bx, Thi = 31 - bx;
  const int n_lo = Tlo + 1, n_hi = Thi + 1;
  const int rL = Tlo * 64 + wave * 16;
  const int rH = Thi * 64 + wave * 16;
  const int rowL = rL + l15;
  const int rowH = rH + l15;

  __shared__ __align__(16) u16 Ks[8 * 512];
  __shared__ __align__(16) u16 Vs[8 * 512];
  __shared__ __align__(16) u16 Pl[4][2][16 * 72];

  u16* PbL = &Pl[wave][0][0];
  u16* PbH = &Pl[wave][1][0];

  const u16* qpL = qb + (size_t)(b * S_ + rL + l15) * EQ_ + h * HD_;
  const u16* qpH = qb + (size_t)(b * S_ + rH + l15) * EQ_ + h * HD_;
  s16x8 qL0 = *(const s16x8*)(qpL + kq);
  s16x8 qL1 = *(const s16x8*)(qpL + 32 + kq);
  s16x8 qH0 = *(const s16x8*)(qpH + kq);
  s16x8 qH1 = *(const s16x8*)(qpH + 32 + kq);

  f32x4 OL[4] = {}, OH[4] = {};
  float sumL = 0.f, sumH = 0.f;

  const int sw = wave & 1;
  const bool doK = (wave < 2);

  // Per-thread staging geometry: waves 0-1 own K (4 HD-chunks each),
  // waves 2-3 own V^T (4 t-chunks each). Chunk i = sw*4+r.
  //   K  src: kb  + (b*S_ + t0 + lane)*EK_ + g*HD_ + i*8   -> Ks[i*512 + lane*8]
  //   V  src: vtb + (g*HD_ + lane)*M_ + b*S_ + t0 + i*8    -> Vs[i*512 + lane*8]
  const u16* stbase;          // source base at t0 = 0, chunk r = 0
  size_t     tstride;         // per-tile source advance (u16 units)
  u16*       ldst;            // LDS dest for chunk r = 0
  if (doK) {
    stbase  = kb + (size_t)(b * S_ + lane) * EK_ + g * HD_ + sw * 32;
    tstride = (size_t)64 * EK_;
    ldst    = &Ks[sw * 4 * 512 + lane * 8];
  } else {
    stbase  = vtb + (size_t)(g * HD_ + lane) * M_ + b * S_ + sw * 32;
    tstride = 64;
    ldst    = &Vs[sw * 4 * 512 + lane * 8];
  }

  // prologue: stage tile 0 direct-to-LDS
  #pragma unroll
  for (int r = 0; r < 4; ++r)
    gl_lds16(stbase + r * 8, ldst + r * 512);
  __syncthreads();

  for (int kt = 0; kt < n_hi; ++kt) {
    const int t0 = kt * 64;

    // ---- issue next tile's loads into registers (overlaps compute below) ----
    const bool pf = (kt + 1 < n_hi);
    uint4 st[4] = {};
    if (pf) {
      const u16* src = stbase + (size_t)(kt + 1) * tstride;
      #pragma unroll
      for (int r = 0; r < 4; ++r)
        st[r] = *(const uint4*)(src + r * 8);
    }

    const bool do_lo = (kt < n_lo);
    const bool mH = (kt == n_hi - 1);
    const bool mL = (kt == n_lo - 1);

    #pragma unroll
    for (int ts = 0; ts < 4; ++ts) {
      s16x8 k0 = *(const s16x8*)&Ks[quad * 512 + (ts * 16 + l15) * 8];
      s16x8 k1 = *(const s16x8*)&Ks[(4 + quad) * 512 + (ts * 16 + l15) * 8];
      const int tb = t0 + ts * 16 + quad * 4;
      {
        f32x4 s = {};
        s = mfma16(k0, qH0, s);
        s = mfma16(k1, qH1, s);
        if (mH) {
          #pragma unroll
          for (int r = 0; r < 4; ++r) if (tb + r > rowH) s[r] = -1e30f;
        }
        float p0 = EXP2(s[0] - EXPOFF), p1 = EXP2(s[1] - EXPOFF);
        float p2 = EXP2(s[2] - EXPOFF), p3 = EXP2(s[3] - EXPOFF);
        sumH += (p0 + p1) + (p2 + p3);
        uint2 w; w.x = pk2(p0, p1); w.y = pk2(p2, p3);
        *(uint2*)&PbH[l15 * 72 + ts * 16 + quad * 4] = w;
      }
      if (do_lo) {
        f32x4 s = {};
        s = mfma16(k0, qL0, s);
        s = mfma16(k1, qL1, s);
        if (mL) {
          #pragma unroll
          for (int r = 0; r < 4; ++r) if (tb + r > rowL) s[r] = -1e30f;
        }
        float p0 = EXP2(s[0] - EXPOFF), p1 = EXP2(s[1] - EXPOFF);
        float p2 = EXP2(s[2] - EXPOFF), p3 = EXP2(s[3] - EXPOFF);
        sumL += (p0 + p1) + (p2 + p3);
        uint2 w; w.x = pk2(p0, p1); w.y = pk2(p2, p3);
        *(uint2*)&PbL[l15 * 72 + ts * 16 + quad * 4] = w;
      }
    }

    s16x8 pH0 = *(const s16x8*)&PbH[l15 * 72 + kq];
    s16x8 pH1 = *(const s16x8*)&PbH[l15 * 72 + 32 + kq];
    s16x8 pL0 = {}, pL1 = {};
    if (do_lo) {
      pL0 = *(const s16x8*)&PbL[l15 * 72 + kq];
      pL1 = *(const s16x8*)&PbL[l15 * 72 + 32 + kq];
    }

    #pragma unroll
    for (int df = 0; df < 4; ++df) {
      s16x8 v0 = *(const s16x8*)&Vs[quad * 512 + (df * 16 + l15) * 8];
      s16x8 v1 = *(const s16x8*)&Vs[(4 + quad) * 512 + (df * 16 + l15) * 8];
      OH[df] = mfma16(v1, pH1, mfma16(v0, pH0, OH[df]));
      if (do_lo) OL[df] = mfma16(v1, pL1, mfma16(v0, pL0, OL[df]));
    }
    __syncthreads();   // all waves done reading Ks/Vs for tile kt

    // ---- land the prefetched tile into LDS ----
    if (pf) {
      #pragma unroll
      for (int r = 0; r < 4; ++r)
        *(uint4*)(ldst + r * 512) = st[r];
    }
    __syncthreads();   // tile kt+1 visible to all waves
  }

  sumH += __shfl_xor(sumH, 16, 64); sumH += __shfl_xor(sumH, 32, 64);
  sumL += __shfl_xor(sumL, 16, 64); sumL += __shfl_xor(sumL, 32, 64);
  float invH = 1.f / sumH, invL = 1.f / sumL;

  {
    u16* op = ob + (size_t)(b * S_ + rowH) * EQ_ + h * HD_;
    #pragma unroll
    for (int df = 0; df < 4; ++df) {
      uint2 w;
      w.x = pk2(OH[df][0] * invH, OH[df][1] * invH);
      w.y = pk2(OH[df][2] * invH, OH[df][3] * invH);
      *(uint2*)(op + df * 16 + quad * 4) = w;
    }
  }
  {
    u16* op = ob + (size_t)(b * S_ + rowL) * EQ_ + h * HD_;
    #pragma unroll
    for (int df = 0; df < 4; ++df) {
      uint2 w;
      w.x = pk2(OL[df][0] * invL, OL[df][1] * invL);
      w.y = pk2(OL[df][2] * invL, OL[df][3] * invL);
      *(uint2*)(op + df * 16 + quad * 4) = w;
    }
  }
}

extern "C" void kernel_launch(void* const* d_in, const int* in_sizes, int n_in,
                              void* d_out, int out_size, void* d_ws, size_t ws_size,
                              hipStream_t stream) {
  (void)in_sizes; (void)n_in; (void)out_size; (void)ws_size;
  const float* x  = (const float*)d_in[0];
  const float* fc = (const float*)d_in[1];
  const float* wq = (const float*)d_in[2];
  const float* wk = (const float*)d_in[3];
  const float* wv = (const float*)d_in[4];
  const float* wo = (const float*)d_in[5];
  float* out = (float*)d_out;
  char* ws = (char*)d_ws;

  u16* xb  = (u16*)(ws);              // 4096x2048
  u16* wqb = (u16*)(ws + 16777216);   // 2048x2048  } contiguous fused [wq;wk;wv]
  u16* wob = (u16*)(ws + 29360128);   // 2048x2048
  u16* qb  = (u16*)(ws + 37748736);   // 4096x2048  (rope'd, x QSCALE)
  u16* kb  = (u16*)(ws + 54525952);   // 4096x512   (rope'd)
  u16* vtb = (u16*)(ws + 58720256);   // 512x4096   (V^T)
  u16* ob  = (u16*)(ws + 62914560);   // 4096x2048

  cast_all<<<18432, 256, 0, stream>>>((const float4*)x, (const float4*)wq,
                                      (const float4*)wk, (const float4*)wv,
                                      (const float4*)wo, (ushort4*)ws);

  gemm_qkv<<<dim3(32, 32), 256, 0, stream>>>(xb, wqb, qb, kb, vtb, fc);

  flash_attn<<<dim3(16, 32, 2), 256, 0, stream>>>(qb, kb, vtb, ob);

  gemm_o<<<dim3(16, 64), 256, 0, stream>>>(ob, wob, out, D_, EQ_);
}

// Round 2
// 324.457 us; speedup vs baseline: 1.4001x; 1.4001x over previous
//
#include <hip/hip_runtime.h>
#include <cstdint>
#include <cstddef>

#define B_ 2
#define S_ 2048
#define D_ 2048
#define H_ 32
#define KV_ 8
#define HD_ 64
#define M_ (B_*S_)      // 4096 rows total
#define EQ_ (H_*HD_)    // 2048
#define EK_ (KV_*HD_)   // 512

typedef unsigned short u16;
typedef __attribute__((ext_vector_type(8))) short s16x8;   // 8 x bf16 (4 VGPRs)
typedef __attribute__((ext_vector_type(4))) float f32x4;

// q pre-scale folds 1/sqrt(HD)=0.125 and log2(e) so flash uses raw 2^x
#define QSCALE 0.18033688011112042f      // 0.125 * log2(e)
#define EXPOFF 15.869645449778564f       // 11 * log2(e)

#if __has_builtin(__builtin_amdgcn_exp2f)
#define EXP2(x) __builtin_amdgcn_exp2f(x)
#else
#define EXP2(x) __expf((x) * 0.6931471805599453f)
#endif

__device__ __forceinline__ u16 f2bf(float f) {
  unsigned u = __float_as_uint(f);
  u += 0x7fffu + ((u >> 16) & 1u);        // RNE
  return (u16)(u >> 16);
}
// pack two floats to two bf16 in one dword via v_perm (proven path)
__device__ __forceinline__ unsigned pk2(float a, float b) {
  unsigned ua = __float_as_uint(a) + 0x8000u;
  unsigned ub = __float_as_uint(b) + 0x8000u;
  return __builtin_amdgcn_perm(ub, ua, 0x07060302);  // [ua.b2,ua.b3,ub.b2,ub.b3]
}
__device__ __forceinline__ f32x4 mfma16(s16x8 a, s16x8 b, f32x4 c) {
  return __builtin_amdgcn_mfma_f32_16x16x32_bf16(a, b, c, 0, 0, 0);
}
__device__ __forceinline__ void gl_lds16(const void* g, void* l) {
  __builtin_amdgcn_global_load_lds(
      (const __attribute__((address_space(1))) void*)g,
      (__attribute__((address_space(3))) void*)l, 16, 0, 0);
}

// ---------------- fused fp32 -> bf16 cast of all 5 inputs ----------------
__global__ void cast_all(const float4* __restrict__ x, const float4* __restrict__ wq,
                         const float4* __restrict__ wk, const float4* __restrict__ wv,
                         const float4* __restrict__ wo, ushort4* __restrict__ dst) {
  int i = blockIdx.x * 256 + threadIdx.x;
  const float4* src; int off;
  if (i < 2097152)      { src = x;  off = i; }
  else if (i < 3145728) { src = wq; off = i - 2097152; }
  else if (i < 3407872) { src = wk; off = i - 3145728; }
  else if (i < 3670016) { src = wv; off = i - 3407872; }
  else                  { src = wo; off = i - 3670016; }
  float4 v = src[off];
  ushort4 r;
  r.x = f2bf(v.x); r.y = f2bf(v.y); r.z = f2bf(v.z); r.w = f2bf(v.w);
  dst[i] = r;
}

// ---------------- fused QKV projection GEMM: 128x96 tile, BK=64, 4 blocks/CU ----------------
// C[m][n] = sum_k X[m][k] * W[n][k], W = [wq; wk; wv] (N=3072 contiguous).
// Grid (32,32)=1024 blocks = 4/CU. XOR-swizzled LDS (0 bank conflicts, R6-proven).
// Region boundaries (2048, 2560) are 16-multiples -> per-ni branch is wave-uniform.
__global__ __launch_bounds__(256)
void gemm_qkv(const u16* __restrict__ A, const u16* __restrict__ Bw,
              u16* __restrict__ qb, u16* __restrict__ kb, u16* __restrict__ vtb,
              const float* __restrict__ fc) {
  __shared__ __align__(16) u16 As[128 * 64];   // 16 KB
  __shared__ __align__(16) u16 Bs[96 * 64];    // 12 KB
  const int tid  = threadIdx.x;
  const int lane = tid & 63;
  const int wave = tid >> 6;
  const int m0 = blockIdx.y * 128;
  const int n0 = blockIdx.x * 96;
  const int wm = (wave >> 1) * 64;
  const int wn = (wave & 1) * 48;
  const int l15 = lane & 15;
  const int quad = lane >> 4;

  f32x4 acc[4][3] = {};

  for (int k0 = 0; k0 < D_; k0 += 64) {
    #pragma unroll
    for (int rr = 0; rr < 4; ++rr) {
      int c = tid + rr * 256;                 // 0..1023: row=c>>3 (0..127)
      int row = c >> 3;
      int ksrc = ((c & 7) ^ (row & 7)) * 8;
      gl_lds16(A + (size_t)(m0 + row) * D_ + k0 + ksrc, &As[c * 8]);
    }
    #pragma unroll
    for (int rr = 0; rr < 3; ++rr) {
      int c = tid + rr * 256;                 // 0..767: row=c>>3 (0..95)
      int row = c >> 3;
      int ksrc = ((c & 7) ^ (row & 7)) * 8;
      gl_lds16(Bw + (size_t)(n0 + row) * D_ + k0 + ksrc, &Bs[c * 8]);
    }
    __syncthreads();

    #pragma unroll
    for (int kc = 0; kc < 2; ++kc) {
      s16x8 af[4], bfr[3];
      #pragma unroll
      for (int mi = 0; mi < 4; ++mi) {
        int row = wm + mi * 16 + l15;
        af[mi]  = *(const s16x8*)&As[row * 64 + (((kc * 4 + quad) ^ (row & 7)) * 8)];
      }
      #pragma unroll
      for (int ni = 0; ni < 3; ++ni) {
        int row = wn + ni * 16 + l15;
        bfr[ni] = *(const s16x8*)&Bs[row * 64 + (((kc * 4 + quad) ^ (row & 7)) * 8)];
      }
      #pragma unroll
      for (int mi = 0; mi < 4; ++mi)
        #pragma unroll
        for (int ni = 0; ni < 3; ++ni)
          acc[mi][ni] = mfma16(af[mi], bfr[ni], acc[mi][ni]);
    }
    __syncthreads();
  }

  // ---- epilogue: per-ni region branch (wave-uniform) ----
  const float sg = (l15 & 1) ? 1.f : -1.f;
  #pragma unroll
  for (int mi = 0; mi < 4; ++mi) {
    #pragma unroll
    for (int ni = 0; ni < 3; ++ni) {
      const int col = n0 + wn + ni * 16 + l15;
      if (col < 2560) {
        // Q or K: fused RoPE (even lane: tr*c - ti*sn; odd: tr*sn + ti*c)
        const bool isQ = (col < 2048);
        u16* dst = isQ ? qb : kb;
        const int ncol0 = isQ ? 0 : 2048;
        const int ndim  = isQ ? EQ_ : EK_;
        const float scale = isQ ? QSCALE : 1.0f;
        const int ip = (col & 63) >> 1;
        #pragma unroll
        for (int r = 0; r < 4; ++r) {
          int row = m0 + wm + mi * 16 + quad * 4 + r;
          const float* fr = fc + (size_t)(row & (S_ - 1)) * 64;
          float c  = fr[ip * 2];
          float sn = fr[ip * 2 + 1];
          float v = acc[mi][ni][r];
          float p = __shfl_xor(v, 1, 64);
          float o = (v * c + sg * (p * sn)) * scale;
          dst[(size_t)row * ndim + col - ncol0] = f2bf(o);
        }
      } else {
        // V: transposed store, 4 consecutive rows per lane -> one 8B store
        const int vcol = col - 2560;
        uint2 w;
        w.x = pk2(acc[mi][ni][0], acc[mi][ni][1]);
        w.y = pk2(acc[mi][ni][2], acc[mi][ni][3]);
        *(uint2*)(vtb + (size_t)vcol * M_ + m0 + wm + mi * 16 + quad * 4) = w;
      }
    }
  }
}

// ---------------- O-projection GEMM: 64x128 tile, BK=64, 4 blocks/CU ----------------
// Grid (16,64)=1024 blocks. 4 waves as 2x2: wave = 32 rows x 64 cols (acc[2][4]).
__global__ __launch_bounds__(256)
void gemm_o(const u16* __restrict__ A, const u16* __restrict__ Bw, float* __restrict__ C,
            int Ndim, int Kdim) {
  __shared__ __align__(16) u16 As[64 * 64];    // 8 KB
  __shared__ __align__(16) u16 Bs[128 * 64];   // 16 KB
  const int tid  = threadIdx.x;
  const int lane = tid & 63;
  const int wave = tid >> 6;
  const int m0 = blockIdx.y * 64;
  const int n0 = blockIdx.x * 128;
  const int wm = (wave >> 1) * 32;
  const int wn = (wave & 1) * 64;
  const int l15 = lane & 15;
  const int quad = lane >> 4;

  f32x4 acc[2][4] = {};

  for (int k0 = 0; k0 < Kdim; k0 += 64) {
    #pragma unroll
    for (int rr = 0; rr < 2; ++rr) {
      int c = tid + rr * 256;                 // 0..511: row=c>>3 (0..63)
      int row = c >> 3;
      int ksrc = ((c & 7) ^ (row & 7)) * 8;
      gl_lds16(A + (size_t)(m0 + row) * Kdim + k0 + ksrc, &As[c * 8]);
    }
    #pragma unroll
    for (int rr = 0; rr < 4; ++rr) {
      int c = tid + rr * 256;                 // 0..1023: row=c>>3 (0..127)
      int row = c >> 3;
      int ksrc = ((c & 7) ^ (row & 7)) * 8;
      gl_lds16(Bw + (size_t)(n0 + row) * Kdim + k0 + ksrc, &Bs[c * 8]);
    }
    __syncthreads();

    #pragma unroll
    for (int kc = 0; kc < 2; ++kc) {
      s16x8 af[2], bfr[4];
      #pragma unroll
      for (int mi = 0; mi < 2; ++mi) {
        int row = wm + mi * 16 + l15;
        af[mi]  = *(const s16x8*)&As[row * 64 + (((kc * 4 + quad) ^ (row & 7)) * 8)];
      }
      #pragma unroll
      for (int ni = 0; ni < 4; ++ni) {
        int row = wn + ni * 16 + l15;
        bfr[ni] = *(const s16x8*)&Bs[row * 64 + (((kc * 4 + quad) ^ (row & 7)) * 8)];
      }
      #pragma unroll
      for (int mi = 0; mi < 2; ++mi)
        #pragma unroll
        for (int ni = 0; ni < 4; ++ni)
          acc[mi][ni] = mfma16(af[mi], bfr[ni], acc[mi][ni]);
    }
    __syncthreads();
  }

  #pragma unroll
  for (int mi = 0; mi < 2; ++mi) {
    #pragma unroll
    for (int r = 0; r < 4; ++r) {
      int row = m0 + wm + mi * 16 + quad * 4 + r;
      size_t base = (size_t)row * Ndim + n0 + wn;
      #pragma unroll
      for (int ni = 0; ni < 4; ++ni)
        C[base + ni * 16 + l15] = acc[mi][ni][r];
    }
  }
}

// ---------------- causal GQA flash attention v6 ----------------
// v4 + LDS-double-buffered K/V with global_load_lds prefetch issued BEFORE
// the compute phase (no data registers -> nothing to spill, unlike v5).
// Single barrier per tile: the vmcnt(0) drain at __syncthreads happens a
// full compute phase (~600-800 cyc) after load issue, hiding HBM/L2 latency.
// LDS 50 KB -> 3 blocks/CU (was 4); latency hiding should dominate.
__global__ __launch_bounds__(256, 4)
void flash_attn(const u16* __restrict__ qb, const u16* __restrict__ kb,
                const u16* __restrict__ vtb, u16* __restrict__ ob) {
  const int bx = blockIdx.x;        // 0..15
  const int h  = blockIdx.y;
  const int b  = blockIdx.z;
  const int g  = h >> 2;            // REP=4
  const int tid  = threadIdx.x;
  const int lane = tid & 63;
  const int wave = tid >> 6;
  const int l15  = lane & 15;
  const int quad = lane >> 4;
  const int kq   = quad * 8;

  const int Tlo = bx, Thi = 31 - bx;
  const int n_lo = Tlo + 1, n_hi = Thi + 1;
  const int rL = Tlo * 64 + wave * 16;
  const int rH = Thi * 64 + wave * 16;
  const int rowL = rL + l15;
  const int rowH = rH + l15;

  __shared__ __align__(16) u16 Ks[2][8 * 512];   // 16 KB (double-buffered)
  __shared__ __align__(16) u16 Vs[2][8 * 512];   // 16 KB (double-buffered)
  __shared__ __align__(16) u16 Pl[4][2][16 * 72];

  u16* PbL = &Pl[wave][0][0];
  u16* PbH = &Pl[wave][1][0];

  const u16* qpL = qb + (size_t)(b * S_ + rL + l15) * EQ_ + h * HD_;
  const u16* qpH = qb + (size_t)(b * S_ + rH + l15) * EQ_ + h * HD_;
  s16x8 qL0 = *(const s16x8*)(qpL + kq);
  s16x8 qL1 = *(const s16x8*)(qpL + 32 + kq);
  s16x8 qH0 = *(const s16x8*)(qpH + kq);
  s16x8 qH1 = *(const s16x8*)(qpH + 32 + kq);

  f32x4 OL[4] = {}, OH[4] = {};
  float sumL = 0.f, sumH = 0.f;

  const int sw = wave & 1;
  const bool doK = (wave < 2);

  // Per-thread staging geometry: waves 0-1 own K (4 HD-chunks each),
  // waves 2-3 own V^T (4 t-chunks each). Chunk i = sw*4+r.
  //   K  src: kb  + (b*S_ + t0 + lane)*EK_ + g*HD_ + i*8   -> Ks[buf][i*512 + lane*8]
  //   V  src: vtb + (g*HD_ + lane)*M_ + b*S_ + t0 + i*8    -> Vs[buf][i*512 + lane*8]
  // LDS dest is wave-uniform base + lane*16B (the required global_load_lds shape).
  const u16* stbase;          // source base at t0 = 0, chunk r = 0
  size_t     tstride;         // per-tile source advance (u16 units)
  int        ldoff;           // offset within one K/V buffer
  if (doK) {
    stbase  = kb + (size_t)(b * S_ + lane) * EK_ + g * HD_ + sw * 32;
    tstride = (size_t)64 * EK_;
  } else {
    stbase  = vtb + (size_t)(g * HD_ + lane) * M_ + b * S_ + sw * 32;
    tstride = 64;
  }
  ldoff = sw * 4 * 512 + lane * 8;
  u16* lbuf0 = doK ? &Ks[0][0] : &Vs[0][0];
  u16* lbuf1 = doK ? &Ks[1][0] : &Vs[1][0];

  // prologue: stage tile 0 into buffer 0
  #pragma unroll
  for (int r = 0; r < 4; ++r)
    gl_lds16(stbase + r * 8, lbuf0 + ldoff + r * 512);
  __syncthreads();

  for (int kt = 0; kt < n_hi; ++kt) {
    const int t0 = kt * 64;
    const u16* kcur = &Ks[kt & 1][0];
    const u16* vcur = &Vs[kt & 1][0];

    // ---- issue next tile's DMA into the other buffer (overlaps compute) ----
    if (kt + 1 < n_hi) {
      u16* dst = (((kt + 1) & 1) ? lbuf1 : lbuf0) + ldoff;
      const u16* src = stbase + (size_t)(kt + 1) * tstride;
      #pragma unroll
      for (int r = 0; r < 4; ++r)
        gl_lds16(src + r * 8, dst + r * 512);
    }

    const bool do_lo = (kt < n_lo);
    const bool mH = (kt == n_hi - 1);
    const bool mL = (kt == n_lo - 1);

    #pragma unroll
    for (int ts = 0; ts < 4; ++ts) {
      s16x8 k0 = *(const s16x8*)&kcur[quad * 512 + (ts * 16 + l15) * 8];
      s16x8 k1 = *(const s16x8*)&kcur[(4 + quad) * 512 + (ts * 16 + l15) * 8];
      const int tb = t0 + ts * 16 + quad * 4;
      {
        f32x4 s = {};
        s = mfma16(k0, qH0, s);
        s = mfma16(k1, qH1, s);
        if (mH) {
          #pragma unroll
          for (int r = 0; r < 4; ++r) if (tb + r > rowH) s[r] = -1e30f;
        }
        float p0 = EXP2(s[0] - EXPOFF), p1 = EXP2(s[1] - EXPOFF);
        float p2 = EXP2(s[2] - EXPOFF), p3 = EXP2(s[3] - EXPOFF);
        sumH += (p0 + p1) + (p2 + p3);
        uint2 w; w.x = pk2(p0, p1); w.y = pk2(p2, p3);
        *(uint2*)&PbH[l15 * 72 + ts * 16 + quad * 4] = w;
      }
      if (do_lo) {
        f32x4 s = {};
        s = mfma16(k0, qL0, s);
        s = mfma16(k1, qL1, s);
        if (mL) {
          #pragma unroll
          for (int r = 0; r < 4; ++r) if (tb + r > rowL) s[r] = -1e30f;
        }
        float p0 = EXP2(s[0] - EXPOFF), p1 = EXP2(s[1] - EXPOFF);
        float p2 = EXP2(s[2] - EXPOFF), p3 = EXP2(s[3] - EXPOFF);
        sumL += (p0 + p1) + (p2 + p3);
        uint2 w; w.x = pk2(p0, p1); w.y = pk2(p2, p3);
        *(uint2*)&PbL[l15 * 72 + ts * 16 + quad * 4] = w;
      }
    }

    s16x8 pH0 = *(const s16x8*)&PbH[l15 * 72 + kq];
    s16x8 pH1 = *(const s16x8*)&PbH[l15 * 72 + 32 + kq];
    s16x8 pL0 = {}, pL1 = {};
    if (do_lo) {
      pL0 = *(const s16x8*)&PbL[l15 * 72 + kq];
      pL1 = *(const s16x8*)&PbL[l15 * 72 + 32 + kq];
    }

    #pragma unroll
    for (int df = 0; df < 4; ++df) {
      s16x8 v0 = *(const s16x8*)&vcur[quad * 512 + (df * 16 + l15) * 8];
      s16x8 v1 = *(const s16x8*)&vcur[(4 + quad) * 512 + (df * 16 + l15) * 8];
      OH[df] = mfma16(v1, pH1, mfma16(v0, pH0, OH[df]));
      if (do_lo) OL[df] = mfma16(v1, pL1, mfma16(v0, pL0, OL[df]));
    }

    // Single barrier: drains this wave's DMA (vmcnt) for tile kt+1 and
    // ensures all waves finished reading buffer kt before it is reused.
    __syncthreads();
  }

  sumH += __shfl_xor(sumH, 16, 64); sumH += __shfl_xor(sumH, 32, 64);
  sumL += __shfl_xor(sumL, 16, 64); sumL += __shfl_xor(sumL, 32, 64);
  float invH = 1.f / sumH, invL = 1.f / sumL;

  {
    u16* op = ob + (size_t)(b * S_ + rowH) * EQ_ + h * HD_;
    #pragma unroll
    for (int df = 0; df < 4; ++df) {
      uint2 w;
      w.x = pk2(OH[df][0] * invH, OH[df][1] * invH);
      w.y = pk2(OH[df][2] * invH, OH[df][3] * invH);
      *(uint2*)(op + df * 16 + quad * 4) = w;
    }
  }
  {
    u16* op = ob + (size_t)(b * S_ + rowL) * EQ_ + h * HD_;
    #pragma unroll
    for (int df = 0; df < 4; ++df) {
      uint2 w;
      w.x = pk2(OL[df][0] * invL, OL[df][1] * invL);
      w.y = pk2(OL[df][2] * invL, OL[df][3] * invL);
      *(uint2*)(op + df * 16 + quad * 4) = w;
    }
  }
}

extern "C" void kernel_launch(void* const* d_in, const int* in_sizes, int n_in,
                              void* d_out, int out_size, void* d_ws, size_t ws_size,
                              hipStream_t stream) {
  (void)in_sizes; (void)n_in; (void)out_size; (void)ws_size;
  const float* x  = (const float*)d_in[0];
  const float* fc = (const float*)d_in[1];
  const float* wq = (const float*)d_in[2];
  const float* wk = (const float*)d_in[3];
  const float* wv = (const float*)d_in[4];
  const float* wo = (const float*)d_in[5];
  float* out = (float*)d_out;
  char* ws = (char*)d_ws;

  u16* xb  = (u16*)(ws);              // 4096x2048
  u16* wqb = (u16*)(ws + 16777216);   // 2048x2048  } contiguous fused [wq;wk;wv]
  u16* wob = (u16*)(ws + 29360128);   // 2048x2048
  u16* qb  = (u16*)(ws + 37748736);   // 4096x2048  (rope'd, x QSCALE)
  u16* kb  = (u16*)(ws + 54525952);   // 4096x512   (rope'd)
  u16* vtb = (u16*)(ws + 58720256);   // 512x4096   (V^T)
  u16* ob  = (u16*)(ws + 62914560);   // 4096x2048

  cast_all<<<18432, 256, 0, stream>>>((const float4*)x, (const float4*)wq,
                                      (const float4*)wk, (const float4*)wv,
                                      (const float4*)wo, (ushort4*)ws);

  gemm_qkv<<<dim3(32, 32), 256, 0, stream>>>(xb, wqb, qb, kb, vtb, fc);

  flash_attn<<<dim3(16, 32, 2), 256, 0, stream>>>(qb, kb, vtb, ob);

  gemm_o<<<dim3(16, 64), 256, 0, stream>>>(ob, wob, out, D_, EQ_);
}

// Round 3
// 301.268 us; speedup vs baseline: 1.5078x; 1.0770x over previous
//
#include <hip/hip_runtime.h>
#include <cstdint>
#include <cstddef>

#define B_ 2
#define S_ 2048
#define D_ 2048
#define H_ 32
#define KV_ 8
#define HD_ 64
#define M_ (B_*S_)      // 4096 rows total
#define EQ_ (H_*HD_)    // 2048
#define EK_ (KV_*HD_)   // 512

typedef unsigned short u16;
typedef __attribute__((ext_vector_type(8))) short s16x8;   // 8 x bf16 (4 VGPRs)
typedef __attribute__((ext_vector_type(4))) float f32x4;

// q pre-scale folds 1/sqrt(HD)=0.125 and log2(e) so flash uses raw 2^x
#define QSCALE 0.18033688011112042f      // 0.125 * log2(e)
#define EXPOFF 15.869645449778564f       // 11 * log2(e)

#if __has_builtin(__builtin_amdgcn_exp2f)
#define EXP2(x) __builtin_amdgcn_exp2f(x)
#else
#define EXP2(x) __expf((x) * 0.6931471805599453f)
#endif

__device__ __forceinline__ u16 f2bf(float f) {
  unsigned u = __float_as_uint(f);
  u += 0x7fffu + ((u >> 16) & 1u);        // RNE
  return (u16)(u >> 16);
}
// pack two floats to two bf16 in one dword via v_perm (proven path)
__device__ __forceinline__ unsigned pk2(float a, float b) {
  unsigned ua = __float_as_uint(a) + 0x8000u;
  unsigned ub = __float_as_uint(b) + 0x8000u;
  return __builtin_amdgcn_perm(ub, ua, 0x07060302);  // [ua.b2,ua.b3,ub.b2,ub.b3]
}
__device__ __forceinline__ f32x4 mfma16(s16x8 a, s16x8 b, f32x4 c) {
  return __builtin_amdgcn_mfma_f32_16x16x32_bf16(a, b, c, 0, 0, 0);
}
__device__ __forceinline__ void gl_lds16(const void* g, void* l) {
  __builtin_amdgcn_global_load_lds(
      (const __attribute__((address_space(1))) void*)g,
      (__attribute__((address_space(3))) void*)l, 16, 0, 0);
}

// ---------------- fused fp32 -> bf16 cast of all 5 inputs ----------------
__global__ void cast_all(const float4* __restrict__ x, const float4* __restrict__ wq,
                         const float4* __restrict__ wk, const float4* __restrict__ wv,
                         const float4* __restrict__ wo, ushort4* __restrict__ dst) {
  int i = blockIdx.x * 256 + threadIdx.x;
  const float4* src; int off;
  if (i < 2097152)      { src = x;  off = i; }
  else if (i < 3145728) { src = wq; off = i - 2097152; }
  else if (i < 3407872) { src = wk; off = i - 3145728; }
  else if (i < 3670016) { src = wv; off = i - 3407872; }
  else                  { src = wo; off = i - 3670016; }
  float4 v = src[off];
  ushort4 r;
  r.x = f2bf(v.x); r.y = f2bf(v.y); r.z = f2bf(v.z); r.w = f2bf(v.w);
  dst[i] = r;
}

// ---------------- fused QKV projection GEMM: 128x96 tile, BK=64, 4 blocks/CU ----------------
// C[m][n] = sum_k X[m][k] * W[n][k], W = [wq; wk; wv] (N=3072 contiguous).
// Grid (32,32)=1024 blocks = 4/CU. XOR-swizzled LDS (0 bank conflicts, R6-proven).
// Region boundaries (2048, 2560) are 16-multiples -> per-ni branch is wave-uniform.
__global__ __launch_bounds__(256)
void gemm_qkv(const u16* __restrict__ A, const u16* __restrict__ Bw,
              u16* __restrict__ qb, u16* __restrict__ kb, u16* __restrict__ vtb,
              const float* __restrict__ fc) {
  __shared__ __align__(16) u16 As[128 * 64];   // 16 KB
  __shared__ __align__(16) u16 Bs[96 * 64];    // 12 KB
  const int tid  = threadIdx.x;
  const int lane = tid & 63;
  const int wave = tid >> 6;
  const int m0 = blockIdx.y * 128;
  const int n0 = blockIdx.x * 96;
  const int wm = (wave >> 1) * 64;
  const int wn = (wave & 1) * 48;
  const int l15 = lane & 15;
  const int quad = lane >> 4;

  f32x4 acc[4][3] = {};

  for (int k0 = 0; k0 < D_; k0 += 64) {
    #pragma unroll
    for (int rr = 0; rr < 4; ++rr) {
      int c = tid + rr * 256;                 // 0..1023: row=c>>3 (0..127)
      int row = c >> 3;
      int ksrc = ((c & 7) ^ (row & 7)) * 8;
      gl_lds16(A + (size_t)(m0 + row) * D_ + k0 + ksrc, &As[c * 8]);
    }
    #pragma unroll
    for (int rr = 0; rr < 3; ++rr) {
      int c = tid + rr * 256;                 // 0..767: row=c>>3 (0..95)
      int row = c >> 3;
      int ksrc = ((c & 7) ^ (row & 7)) * 8;
      gl_lds16(Bw + (size_t)(n0 + row) * D_ + k0 + ksrc, &Bs[c * 8]);
    }
    __syncthreads();

    #pragma unroll
    for (int kc = 0; kc < 2; ++kc) {
      s16x8 af[4], bfr[3];
      #pragma unroll
      for (int mi = 0; mi < 4; ++mi) {
        int row = wm + mi * 16 + l15;
        af[mi]  = *(const s16x8*)&As[row * 64 + (((kc * 4 + quad) ^ (row & 7)) * 8)];
      }
      #pragma unroll
      for (int ni = 0; ni < 3; ++ni) {
        int row = wn + ni * 16 + l15;
        bfr[ni] = *(const s16x8*)&Bs[row * 64 + (((kc * 4 + quad) ^ (row & 7)) * 8)];
      }
      #pragma unroll
      for (int mi = 0; mi < 4; ++mi)
        #pragma unroll
        for (int ni = 0; ni < 3; ++ni)
          acc[mi][ni] = mfma16(af[mi], bfr[ni], acc[mi][ni]);
    }
    __syncthreads();
  }

  // ---- epilogue: per-ni region branch (wave-uniform) ----
  const float sg = (l15 & 1) ? 1.f : -1.f;
  #pragma unroll
  for (int mi = 0; mi < 4; ++mi) {
    #pragma unroll
    for (int ni = 0; ni < 3; ++ni) {
      const int col = n0 + wn + ni * 16 + l15;
      if (col < 2560) {
        // Q or K: fused RoPE (even lane: tr*c - ti*sn; odd: tr*sn + ti*c)
        const bool isQ = (col < 2048);
        u16* dst = isQ ? qb : kb;
        const int ncol0 = isQ ? 0 : 2048;
        const int ndim  = isQ ? EQ_ : EK_;
        const float scale = isQ ? QSCALE : 1.0f;
        const int ip = (col & 63) >> 1;
        #pragma unroll
        for (int r = 0; r < 4; ++r) {
          int row = m0 + wm + mi * 16 + quad * 4 + r;
          const float* fr = fc + (size_t)(row & (S_ - 1)) * 64;
          float c  = fr[ip * 2];
          float sn = fr[ip * 2 + 1];
          float v = acc[mi][ni][r];
          float p = __shfl_xor(v, 1, 64);
          float o = (v * c + sg * (p * sn)) * scale;
          dst[(size_t)row * ndim + col - ncol0] = f2bf(o);
        }
      } else {
        // V: transposed store, 4 consecutive rows per lane -> one 8B store
        const int vcol = col - 2560;
        uint2 w;
        w.x = pk2(acc[mi][ni][0], acc[mi][ni][1]);
        w.y = pk2(acc[mi][ni][2], acc[mi][ni][3]);
        *(uint2*)(vtb + (size_t)vcol * M_ + m0 + wm + mi * 16 + quad * 4) = w;
      }
    }
  }
}

// ---------------- O-projection GEMM: 64x128 tile, BK=64, 4 blocks/CU ----------------
// Grid (16,64)=1024 blocks. 4 waves as 2x2: wave = 32 rows x 64 cols (acc[2][4]).
__global__ __launch_bounds__(256)
void gemm_o(const u16* __restrict__ A, const u16* __restrict__ Bw, float* __restrict__ C,
            int Ndim, int Kdim) {
  __shared__ __align__(16) u16 As[64 * 64];    // 8 KB
  __shared__ __align__(16) u16 Bs[128 * 64];   // 16 KB
  const int tid  = threadIdx.x;
  const int lane = tid & 63;
  const int wave = tid >> 6;
  const int m0 = blockIdx.y * 64;
  const int n0 = blockIdx.x * 128;
  const int wm = (wave >> 1) * 32;
  const int wn = (wave & 1) * 64;
  const int l15 = lane & 15;
  const int quad = lane >> 4;

  f32x4 acc[2][4] = {};

  for (int k0 = 0; k0 < Kdim; k0 += 64) {
    #pragma unroll
    for (int rr = 0; rr < 2; ++rr) {
      int c = tid + rr * 256;                 // 0..511: row=c>>3 (0..63)
      int row = c >> 3;
      int ksrc = ((c & 7) ^ (row & 7)) * 8;
      gl_lds16(A + (size_t)(m0 + row) * Kdim + k0 + ksrc, &As[c * 8]);
    }
    #pragma unroll
    for (int rr = 0; rr < 4; ++rr) {
      int c = tid + rr * 256;                 // 0..1023: row=c>>3 (0..127)
      int row = c >> 3;
      int ksrc = ((c & 7) ^ (row & 7)) * 8;
      gl_lds16(Bw + (size_t)(n0 + row) * Kdim + k0 + ksrc, &Bs[c * 8]);
    }
    __syncthreads();

    #pragma unroll
    for (int kc = 0; kc < 2; ++kc) {
      s16x8 af[2], bfr[4];
      #pragma unroll
      for (int mi = 0; mi < 2; ++mi) {
        int row = wm + mi * 16 + l15;
        af[mi]  = *(const s16x8*)&As[row * 64 + (((kc * 4 + quad) ^ (row & 7)) * 8)];
      }
      #pragma unroll
      for (int ni = 0; ni < 4; ++ni) {
        int row = wn + ni * 16 + l15;
        bfr[ni] = *(const s16x8*)&Bs[row * 64 + (((kc * 4 + quad) ^ (row & 7)) * 8)];
      }
      #pragma unroll
      for (int mi = 0; mi < 2; ++mi)
        #pragma unroll
        for (int ni = 0; ni < 4; ++ni)
          acc[mi][ni] = mfma16(af[mi], bfr[ni], acc[mi][ni]);
    }
    __syncthreads();
  }

  #pragma unroll
  for (int mi = 0; mi < 2; ++mi) {
    #pragma unroll
    for (int r = 0; r < 4; ++r) {
      int row = m0 + wm + mi * 16 + quad * 4 + r;
      size_t base = (size_t)row * Ndim + n0 + wn;
      #pragma unroll
      for (int ni = 0; ni < 4; ++ni)
        C[base + ni * 16 + l15] = acc[mi][ni][r];
    }
  }
}

// ---------------- causal GQA flash attention v7 ----------------
// v4 structure + K double-buffer + early DMA issue, in exactly 40 KB LDS
// (4 blocks/CU preserved):
//   - Ks[2]: K(kt+1) DMA issued at top of iter kt, drained at mid-barrier
//     (window = QK^T+softmax, ~500 cyc) -> K latency hidden.
//   - Vs single: V(kt) DMA issued at top of iter kt (Vs freed by prev end
//     barrier), drained at mid-barrier -> V latency hidden under same window.
//   - Pl shrunk 18->16 KB via stride-64 XOR swizzle (byte ^= (l15&7)<<4
//     within each 128B row); same 2-way bank pattern as the 72-stride pad.
// Total: 16 (Ks) + 8 (Vs) + 16 (Pl) = 40960 B. 2 barriers/tile like v4, but
// no barrier ever waits on a freshly-issued load.
__global__ __launch_bounds__(256, 4)
void flash_attn(const u16* __restrict__ qb, const u16* __restrict__ kb,
                const u16* __restrict__ vtb, u16* __restrict__ ob) {
  const int bx = blockIdx.x;        // 0..15
  const int h  = blockIdx.y;
  const int b  = blockIdx.z;
  const int g  = h >> 2;            // REP=4
  const int tid  = threadIdx.x;
  const int lane = tid & 63;
  const int wave = tid >> 6;
  const int l15  = lane & 15;
  const int quad = lane >> 4;
  const int kq   = quad * 8;

  const int Tlo = bx, Thi = 31 - bx;
  const int n_lo = Tlo + 1, n_hi = Thi + 1;
  const int rL = Tlo * 64 + wave * 16;
  const int rH = Thi * 64 + wave * 16;
  const int rowL = rL + l15;
  const int rowH = rH + l15;

  __shared__ __align__(16) u16 Ks[2][8 * 512];   // 16 KB (K double-buffered)
  __shared__ __align__(16) u16 Vs[8 * 512];      //  8 KB (V single)
  __shared__ __align__(16) u16 Pl[4][2][16 * 64];// 16 KB (XOR-swizzled, no pad)

  char* PbL = (char*)&Pl[wave][0][0];
  char* PbH = (char*)&Pl[wave][1][0];
  const int pm = (l15 & 7) << 4;    // per-lane XOR mask for P rows

  const u16* qpL = qb + (size_t)(b * S_ + rL + l15) * EQ_ + h * HD_;
  const u16* qpH = qb + (size_t)(b * S_ + rH + l15) * EQ_ + h * HD_;
  s16x8 qL0 = *(const s16x8*)(qpL + kq);
  s16x8 qL1 = *(const s16x8*)(qpL + 32 + kq);
  s16x8 qH0 = *(const s16x8*)(qpH + kq);
  s16x8 qH1 = *(const s16x8*)(qpH + 32 + kq);

  f32x4 OL[4] = {}, OH[4] = {};
  float sumL = 0.f, sumH = 0.f;

  const int sw = wave & 1;
  const bool doK = (wave < 2);

  // Staging geometry: waves 0-1 own K (chunk i = sw*4+r over HD), waves 2-3
  // own V^T (chunk i over t). LDS dest = wave-uniform base + lane*16B.
  const u16* stbase;          // source base at t0 = 0, chunk r = 0
  size_t     tstride;         // per-tile source advance (u16 units)
  if (doK) {
    stbase  = kb + (size_t)(b * S_ + lane) * EK_ + g * HD_ + sw * 32;
    tstride = (size_t)64 * EK_;
  } else {
    stbase  = vtb + (size_t)(g * HD_ + lane) * M_ + b * S_ + sw * 32;
    tstride = 64;
  }
  const int ldoff = sw * 4 * 512 + lane * 8;   // u16 offset within a K/V buffer

  // prologue: stage K(0) into Ks[0] (V(0) is issued inside iter 0)
  if (doK) {
    #pragma unroll
    for (int r = 0; r < 4; ++r)
      gl_lds16(stbase + r * 8, &Ks[0][ldoff + r * 512]);
  }
  __syncthreads();

  for (int kt = 0; kt < n_hi; ++kt) {
    const int t0 = kt * 64;
    const u16* kcur = &Ks[kt & 1][0];

    // ---- issue this tile's V and next tile's K (both drain at mid-barrier) ----
    if (doK) {
      if (kt + 1 < n_hi) {
        const u16* src = stbase + (size_t)(kt + 1) * tstride;
        u16* dst = &Ks[(kt + 1) & 1][ldoff];
        #pragma unroll
        for (int r = 0; r < 4; ++r)
          gl_lds16(src + r * 8, dst + r * 512);
      }
    } else {
      const u16* src = stbase + (size_t)kt * tstride;
      #pragma unroll
      for (int r = 0; r < 4; ++r)
        gl_lds16(src + r * 8, &Vs[ldoff + r * 512]);
    }

    const bool do_lo = (kt < n_lo);
    const bool mH = (kt == n_hi - 1);
    const bool mL = (kt == n_lo - 1);

    #pragma unroll
    for (int ts = 0; ts < 4; ++ts) {
      s16x8 k0 = *(const s16x8*)&kcur[quad * 512 + (ts * 16 + l15) * 8];
      s16x8 k1 = *(const s16x8*)&kcur[(4 + quad) * 512 + (ts * 16 + l15) * 8];
      const int tb = t0 + ts * 16 + quad * 4;
      {
        f32x4 s = {};
        s = mfma16(k0, qH0, s);
        s = mfma16(k1, qH1, s);
        if (mH) {
          #pragma unroll
          for (int r = 0; r < 4; ++r) if (tb + r > rowH) s[r] = -1e30f;
        }
        float p0 = EXP2(s[0] - EXPOFF), p1 = EXP2(s[1] - EXPOFF);
        float p2 = EXP2(s[2] - EXPOFF), p3 = EXP2(s[3] - EXPOFF);
        sumH += (p0 + p1) + (p2 + p3);
        uint2 w; w.x = pk2(p0, p1); w.y = pk2(p2, p3);
        *(uint2*)(PbH + l15 * 128 + ((ts * 32 + quad * 8) ^ pm)) = w;
      }
      if (do_lo) {
        f32x4 s = {};
        s = mfma16(k0, qL0, s);
        s = mfma16(k1, qL1, s);
        if (mL) {
          #pragma unroll
          for (int r = 0; r < 4; ++r) if (tb + r > rowL) s[r] = -1e30f;
        }
        float p0 = EXP2(s[0] - EXPOFF), p1 = EXP2(s[1] - EXPOFF);
        float p2 = EXP2(s[2] - EXPOFF), p3 = EXP2(s[3] - EXPOFF);
        sumL += (p0 + p1) + (p2 + p3);
        uint2 w; w.x = pk2(p0, p1); w.y = pk2(p2, p3);
        *(uint2*)(PbL + l15 * 128 + ((ts * 32 + quad * 8) ^ pm)) = w;
      }
    }

    s16x8 pH0 = *(const s16x8*)(PbH + l15 * 128 + ((quad * 16) ^ pm));
    s16x8 pH1 = *(const s16x8*)(PbH + l15 * 128 + ((64 + quad * 16) ^ pm));
    s16x8 pL0 = {}, pL1 = {};
    if (do_lo) {
      pL0 = *(const s16x8*)(PbL + l15 * 128 + ((quad * 16) ^ pm));
      pL1 = *(const s16x8*)(PbL + l15 * 128 + ((64 + quad * 16) ^ pm));
    }

    // mid-barrier: V(kt) and K(kt+1) DMAs drain here, a full QK^T+softmax
    // phase after issue.
    __syncthreads();

    #pragma unroll
    for (int df = 0; df < 4; ++df) {
      s16x8 v0 = *(const s16x8*)&Vs[quad * 512 + (df * 16 + l15) * 8];
      s16x8 v1 = *(const s16x8*)&Vs[(4 + quad) * 512 + (df * 16 + l15) * 8];
      OH[df] = mfma16(v1, pH1, mfma16(v0, pH0, OH[df]));
      if (do_lo) OL[df] = mfma16(v1, pL1, mfma16(v0, pL0, OL[df]));
    }

    // end-barrier: all waves done reading Ks[kt&1]/Vs; next iter may issue
    // DMA into them (vmcnt is already 0 here -> cheap drain).
    __syncthreads();
  }

  sumH += __shfl_xor(sumH, 16, 64); sumH += __shfl_xor(sumH, 32, 64);
  sumL += __shfl_xor(sumL, 16, 64); sumL += __shfl_xor(sumL, 32, 64);
  float invH = 1.f / sumH, invL = 1.f / sumL;

  {
    u16* op = ob + (size_t)(b * S_ + rowH) * EQ_ + h * HD_;
    #pragma unroll
    for (int df = 0; df < 4; ++df) {
      uint2 w;
      w.x = pk2(OH[df][0] * invH, OH[df][1] * invH);
      w.y = pk2(OH[df][2] * invH, OH[df][3] * invH);
      *(uint2*)(op + df * 16 + quad * 4) = w;
    }
  }
  {
    u16* op = ob + (size_t)(b * S_ + rowL) * EQ_ + h * HD_;
    #pragma unroll
    for (int df = 0; df < 4; ++df) {
      uint2 w;
      w.x = pk2(OL[df][0] * invL, OL[df][1] * invL);
      w.y = pk2(OL[df][2] * invL, OL[df][3] * invL);
      *(uint2*)(op + df * 16 + quad * 4) = w;
    }
  }
}

extern "C" void kernel_launch(void* const* d_in, const int* in_sizes, int n_in,
                              void* d_out, int out_size, void* d_ws, size_t ws_size,
                              hipStream_t stream) {
  (void)in_sizes; (void)n_in; (void)out_size; (void)ws_size;
  const float* x  = (const float*)d_in[0];
  const float* fc = (const float*)d_in[1];
  const float* wq = (const float*)d_in[2];
  const float* wk = (const float*)d_in[3];
  const float* wv = (const float*)d_in[4];
  const float* wo = (const float*)d_in[5];
  float* out = (float*)d_out;
  char* ws = (char*)d_ws;

  u16* xb  = (u16*)(ws);              // 4096x2048
  u16* wqb = (u16*)(ws + 16777216);   // 2048x2048  } contiguous fused [wq;wk;wv]
  u16* wob = (u16*)(ws + 29360128);   // 2048x2048
  u16* qb  = (u16*)(ws + 37748736);   // 4096x2048  (rope'd, x QSCALE)
  u16* kb  = (u16*)(ws + 54525952);   // 4096x512   (rope'd)
  u16* vtb = (u16*)(ws + 58720256);   // 512x4096   (V^T)
  u16* ob  = (u16*)(ws + 62914560);   // 4096x2048

  cast_all<<<18432, 256, 0, stream>>>((const float4*)x, (const float4*)wq,
                                      (const float4*)wk, (const float4*)wv,
                                      (const float4*)wo, (ushort4*)ws);

  gemm_qkv<<<dim3(32, 32), 256, 0, stream>>>(xb, wqb, qb, kb, vtb, fc);

  flash_attn<<<dim3(16, 32, 2), 256, 0, stream>>>(qb, kb, vtb, ob);

  gemm_o<<<dim3(16, 64), 256, 0, stream>>>(ob, wob, out, D_, EQ_);
}